// Round 2
// baseline (135.624 us; speedup 1.0000x reference)
//
#include <hip/hip_runtime.h>
#include <hip/hip_bf16.h>

// ROC-AUC loss via Fourier CDF approximation.
// k_detect  (1 block):   detect targets dtype (bool-as-u8 / i32 / f32) from raw
//                        bytes, publish a single `mode` word; zero the accumulator.
// k_partial (512 blocks): masked sums of sin/cos(2*pi*k*s), k=1..128, pos-class
//                        and total (neg = total - pos). Chunk staged in LDS as
//                        float2(score,mask); 1 harmonic per thread (x2 halves);
//                        hardware v_sin/v_cos in revolutions: sin(2pi*k*s) =
//                        v_sin(v_fract(k*s)). Block results atomicAdd'ed into
//                        a 513-float global accumulator (no partials array).
// k_final   (1 block):   integrated Fourier coeffs, normalized CDFs at 1024
//                        thresholds (1/thread), Riemann AUC, write scalar.

#define NK 128
#define NSTEPS 1024
#define K1_TPB 256
#define CHUNK 512
#define DET_TPB 1024
#define K2_TPB 1024

__device__ __forceinline__ float wave_sum(float v) {
  #pragma unroll
  for (int off = 32; off > 0; off >>= 1) v += __shfl_down(v, off, 64);
  return v;
}

// Block-reduce to thread 0. scratch >= blockDim/64 floats.
__device__ __forceinline__ float block_sum(float v, float* scratch) {
  int lane = threadIdx.x & 63, wid = threadIdx.x >> 6;
  v = wave_sum(v);
  if (lane == 0) scratch[wid] = v;
  __syncthreads();
  float r = 0.0f;
  if (threadIdx.x == 0) {
    int nw = blockDim.x >> 6;
    for (int w = 0; w < nw; ++w) r += scratch[w];
  }
  return r;
}

// ---- dtype detect + accumulator zero (single block) ----
// Scans only the first N BYTES (safe under every interpretation), byte-lane OR:
// i32 {0,1} -> 0x00000001 ; u8 {0,1} -> nonzero in multiple byte lanes ;
// f32 {0.0,1.0} -> 0x3F800000. All-zero -> mode 0 (u8 read is the narrowest,
// always in-bounds, and decodes 0 correctly under any true dtype).
__global__ __launch_bounds__(DET_TPB) void k_detect(const unsigned char* __restrict__ t,
                                                    int nbytes,
                                                    unsigned* __restrict__ mode_out,
                                                    float* __restrict__ acc) {
  __shared__ unsigned s_or;
  const int tid = threadIdx.x;
  if (tid == 0) s_or = 0u;
  if (tid < NK * 4 + 4) acc[tid] = 0.0f;  // zero 516 floats (513 used)
  __syncthreads();
  unsigned local = 0u;
  int n16 = nbytes >> 4;
  const uint4* p = (const uint4*)t;
  for (int i = tid; i < n16; i += DET_TPB) {
    uint4 v = p[i];
    local |= v.x | v.y | v.z | v.w;
  }
  if (tid < (nbytes & 15)) {
    int i = (n16 << 4) + tid;
    local |= ((unsigned)t[i]) << ((i & 3) * 8);
  }
  if (local) atomicOr(&s_or, local);
  __syncthreads();
  if (tid == 0) {
    unsigned o = s_or;
    bool nz0 = (o & 0xFFu) != 0u;
    bool nz1 = (o & 0xFF00u) != 0u;
    bool nz23 = (o & 0xFFFF0000u) != 0u;
    unsigned mode = 0u;                        // u8 / bool (and the all-zero case)
    if (o != 0u) {
      if (!nz1 && !nz23) mode = 1u;            // int32 values {0,1}
      else if (!nz0 && !nz1) mode = 2u;        // float32 values {0.0,1.0}
    }
    mode_out[0] = mode;
  }
}

// ---- phase 1: masked Fourier sums, atomically accumulated ----
__global__ __launch_bounds__(K1_TPB) void k_partial(const float* __restrict__ scores,
                                                    const unsigned char* __restrict__ tgt,
                                                    int N,
                                                    const unsigned* __restrict__ mode_ptr,
                                                    float* __restrict__ acc) {
  __shared__ float2 s_d[CHUNK];       // (score, mask)
  __shared__ float s_comb[NK * 4];    // half==1 partials for combine
  __shared__ float s_red[K1_TPB / 64];
  __shared__ unsigned s_mode;
  if (threadIdx.x == 0) s_mode = mode_ptr[0];
  __syncthreads();
  const int mode = (int)s_mode;
  const int base = blockIdx.x * CHUNK;

  float lc = 0.0f;  // positive count (each sample loaded exactly once)
  for (int i = threadIdx.x; i < CHUNK; i += K1_TPB) {
    int g = base + i;
    float s = 0.0f, m = 0.0f;
    if (g < N) {
      s = scores[g];
      if (mode == 0)      m = (float)tgt[g];
      else if (mode == 1) m = (float)((const int*)tgt)[g];
      else                m = ((const float*)tgt)[g];
    }
    s_d[i] = make_float2(s, m);
    lc += m;
  }
  __syncthreads();
  float cnt = block_sum(lc, s_red);  // valid on thread 0 only

  const int k_idx = threadIdx.x & (NK - 1);
  const int half = threadIdx.x >> 7;  // 0 or 1
  const float kf = (float)(k_idx + 1);
  const int HC = CHUNK / 2;
  const int i0 = half * HC;

  float ps = 0.0f, pc = 0.0f, ts = 0.0f, tc = 0.0f;
  #pragma unroll 4
  for (int i = 0; i < HC; ++i) {
    float2 d = s_d[i0 + i];  // LDS broadcast (same addr across wave) - no conflicts
    float x = kf * d.x;
    float f = __builtin_amdgcn_fractf(x);         // k*s mod 1 (revolutions)
    float sn = __builtin_amdgcn_sinf(f);          // sin(2*pi*k*s)
    float cs = __builtin_amdgcn_cosf(f);          // cos(2*pi*k*s)
    ts += sn;
    tc += cs;
    ps = fmaf(d.y, sn, ps);
    pc = fmaf(d.y, cs, pc);
  }
  // padded (g>=N) entries have s=0,m=0 -> contributed cos(0)=1 to tc only; remove
  int valid = min(max(N - base - i0, 0), HC);
  tc -= (float)(HC - valid);

  if (half == 1) {
    s_comb[k_idx * 4 + 0] = ps;
    s_comb[k_idx * 4 + 1] = pc;
    s_comb[k_idx * 4 + 2] = ts;
    s_comb[k_idx * 4 + 3] = tc;
  }
  __syncthreads();
  if (half == 0) {
    atomicAdd(&acc[k_idx * 4 + 0], ps + s_comb[k_idx * 4 + 0]);
    atomicAdd(&acc[k_idx * 4 + 1], pc + s_comb[k_idx * 4 + 1]);
    atomicAdd(&acc[k_idx * 4 + 2], ts + s_comb[k_idx * 4 + 2]);
    atomicAdd(&acc[k_idx * 4 + 3], tc + s_comb[k_idx * 4 + 3]);
  }
  if (threadIdx.x == 0) atomicAdd(&acc[NK * 4], cnt);
}

// ---- phase 2: coefficients, CDF eval, AUC ----
__global__ __launch_bounds__(K2_TPB) void k_final(const float* __restrict__ acc,
                                                  int N,
                                                  float* __restrict__ out) {
  __shared__ float s_sums[NK * 4];
  __shared__ float s_isp[NK], s_icp[NK], s_isn[NK], s_icn[NK];
  __shared__ float s_pn[NSTEPS + 2], s_nn[NSTEPS + 2];
  __shared__ float s_red[K2_TPB / 64];
  __shared__ float s_npos;
  const int tid = threadIdx.x;

  if (tid < NK * 4) s_sums[tid] = acc[tid];
  if (tid == 0) s_npos = acc[NK * 4];
  __syncthreads();

  // Phase B: integrated Fourier coefficients for both classes
  if (tid < NK) {
    const float eps = 1.1920929e-07f;  // FLT_EPSILON, matches jnp.finfo(f32).eps
    float npos = s_npos;
    float nneg = (float)N - npos;
    float sp = s_sums[tid * 4 + 0], cp = s_sums[tid * 4 + 1];
    float st = s_sums[tid * 4 + 2], ct = s_sums[tid * 4 + 3];
    float scp, ccp, scn, ccn;
    if (npos < eps) { scp = 0.0f; ccp = 0.0f; }
    else { float d = fmaxf(npos, eps); scp = sp / d; ccp = cp / d; }
    if (nneg < eps) { scn = 0.0f; ccn = 0.0f; }
    else { float d = fmaxf(nneg, eps); scn = (st - sp) / d; ccn = (ct - cp) / d; }
    float w = 6.2831853071795864769f * (float)(tid + 1);  // fl(2*pi)*k, as reference
    s_isp[tid] = ccp / w;  s_icp[tid] = -scp / w;
    s_isn[tid] = ccn / w;  s_icn[tid] = -scn / w;
  }
  __syncthreads();

  // Phase C: normalized CDFs at 1024 thresholds, one per thread
  {
    float thr = (float)tid * (1.0f / 1023.0f);
    float cp_acc = 0.0f, cn_acc = 0.0f;
    #pragma unroll 4
    for (int k = 0; k < NK; ++k) {
      float x = (float)(k + 1) * thr;
      float f = __builtin_amdgcn_fractf(x);
      float sn = __builtin_amdgcn_sinf(f);
      float cs = __builtin_amdgcn_cosf(f);
      cp_acc += sn * s_isp[k] + cs * s_icp[k];
      cn_acc += sn * s_isn[k] + cs * s_icn[k];
    }
    s_pn[tid + 1] = 1.0f - 0.5f * (cp_acc + 0.5f);
    s_nn[tid + 1] = 1.0f - 0.5f * (cn_acc + 0.5f);
  }
  if (tid == 0) {
    s_pn[0] = 1.0f; s_nn[0] = 1.0f;
    s_pn[NSTEPS + 1] = 0.0f; s_nn[NSTEPS + 1] = 0.0f;
  }
  __syncthreads();

  // Phase D: Riemann AUC both directions
  float pa = 0.0f, na = 0.0f;
  for (int i = tid; i < NSTEPS + 1; i += K2_TPB) {
    float p0 = s_pn[i], p1 = s_pn[i + 1];
    float n0 = s_nn[i], n1 = s_nn[i + 1];
    pa = fmaf(p0, n0 - n1, pa);   // pos_norm[i] * (-diff(neg_norm))[i]
    na = fmaf(n0, p1 - p0, na);   // neg_norm[i] * diff(pos_norm)[i]
  }
  float paS = block_sum(pa, s_red);
  __syncthreads();
  float naS = block_sum(na, s_red);
  if (tid == 0) out[0] = 0.5f * (paS + (1.0f + naS));
}

extern "C" void kernel_launch(void* const* d_in, const int* in_sizes, int n_in,
                              void* d_out, int out_size, void* d_ws, size_t ws_size,
                              hipStream_t stream) {
  const float* scores = (const float*)d_in[0];
  const unsigned char* targets = (const unsigned char*)d_in[1];
  const int N = in_sizes[0];

  unsigned* mode_ptr = (unsigned*)d_ws;
  float* acc = (float*)((char*)d_ws + 64);

  const int nblocks = (N + CHUNK - 1) / CHUNK;  // 512 for N=262144

  k_detect<<<1, DET_TPB, 0, stream>>>(targets, N, mode_ptr, acc);
  k_partial<<<nblocks, K1_TPB, 0, stream>>>(scores, targets, N, mode_ptr, acc);
  k_final<<<1, K2_TPB, 0, stream>>>(acc, N, (float*)d_out);
}

// Round 3
// 93.882 us; speedup vs baseline: 1.4446x; 1.4446x over previous
//
#include <hip/hip_runtime.h>
#include <hip/hip_bf16.h>

// ROC-AUC loss via Fourier CDF approximation.
// k_detect  (64 blocks): detect targets dtype (u8-bool / i32 / f32) from raw
//                        bytes (per-block OR word), zero the replica accumulators.
// k_partial (1024 blocks, CHUNK=256): masked sums of sin/cos(2*pi*k*s), k=1..128,
//                        pos-class and total (neg = total - pos). Chunk in LDS as
//                        float2(score,mask); 1 harmonic per thread (x2 halves);
//                        hw v_sin/v_cos in revolutions: sin(2pi*k*s)=v_sin(fract(k*s)).
//                        8-wide LDS batches + split accumulators for latency hiding.
//                        Block results atomicAdd'ed into 1-of-8 replica accumulators.
// k_final   (1 block):   sum replicas, integrated Fourier coeffs, normalized CDFs
//                        at 1024 thresholds (1/thread), Riemann AUC, write scalar.

#define NK 128
#define NSTEPS 1024
#define K1_TPB 256
#define CHUNK 256
#define REP 8
#define RSTRIDE 520          // floats per replica row: 512 sums + count + pad
#define DET_BLOCKS 64
#define DET_TPB 256
#define K2_TPB 1024

__device__ __forceinline__ float wave_sum(float v) {
  #pragma unroll
  for (int off = 32; off > 0; off >>= 1) v += __shfl_down(v, off, 64);
  return v;
}

// Block-reduce to thread 0. scratch >= blockDim/64 floats.
__device__ __forceinline__ float block_sum(float v, float* scratch) {
  int lane = threadIdx.x & 63, wid = threadIdx.x >> 6;
  v = wave_sum(v);
  if (lane == 0) scratch[wid] = v;
  __syncthreads();
  float r = 0.0f;
  if (threadIdx.x == 0) {
    int nw = blockDim.x >> 6;
    for (int w = 0; w < nw; ++w) r += scratch[w];
  }
  return r;
}

// ---- dtype detect (per-block OR word) + zero replica accumulators ----
// Scans only the first N BYTES (in-bounds under every dtype interpretation).
// i32 {0,1} -> only byte-lane0 set ; u8 {0,1} -> multiple byte lanes set ;
// f32 {0.0,1.0} -> 0x3F800000 (lanes 2,3). All-zero -> u8 read (all masks 0
// under any true dtype -> identical result).
__global__ __launch_bounds__(DET_TPB) void k_detect(const unsigned char* __restrict__ t,
                                                    int nbytes,
                                                    unsigned* __restrict__ flags,
                                                    float* __restrict__ acc) {
  __shared__ unsigned s_or;
  const int gid = blockIdx.x * DET_TPB + threadIdx.x;
  if (threadIdx.x == 0) s_or = 0u;
  for (int i = gid; i < REP * RSTRIDE; i += DET_BLOCKS * DET_TPB) acc[i] = 0.0f;
  __syncthreads();
  unsigned local = 0u;
  int n16 = nbytes >> 4;
  const uint4* p = (const uint4*)t;
  for (int i = gid; i < n16; i += DET_BLOCKS * DET_TPB) {
    uint4 v = p[i];
    local |= v.x | v.y | v.z | v.w;
  }
  if (gid < (nbytes & 15)) {            // tail bytes (gid<16 lives in block 0)
    int i = (n16 << 4) + gid;
    local |= ((unsigned)t[i]) << ((i & 3) * 8);
  }
  if (local) atomicOr(&s_or, local);
  __syncthreads();
  if (threadIdx.x == 0) flags[blockIdx.x] = s_or;
}

__device__ __forceinline__ int decode_mode(const unsigned* __restrict__ flags) {
  unsigned o = 0u;
  #pragma unroll
  for (int i = 0; i < DET_BLOCKS; ++i) o |= flags[i];   // uniform -> s_loads
  if (o == 0u) return 0;
  bool nz0 = (o & 0xFFu) != 0u;
  bool nz1 = (o & 0xFF00u) != 0u;
  if (!nz1 && !(o & 0xFFFF0000u)) return 1;  // int32 values {0,1}
  if (!nz0 && !nz1) return 2;                // float32 values {0.0,1.0}
  return 0;                                  // uint8 / bool
}

// ---- phase 1: masked Fourier sums, atomically accumulated into replicas ----
__global__ __launch_bounds__(K1_TPB) void k_partial(const float* __restrict__ scores,
                                                    const unsigned char* __restrict__ tgt,
                                                    int N,
                                                    const unsigned* __restrict__ flags,
                                                    float* __restrict__ acc) {
  __shared__ float2 s_d[CHUNK];       // (score, mask)
  __shared__ float s_comb[NK * 4];    // half==1 partials for combine
  __shared__ float s_red[K1_TPB / 64];
  __shared__ int s_mode;
  if (threadIdx.x == 0) s_mode = decode_mode(flags);
  __syncthreads();
  const int mode = s_mode;
  const int base = blockIdx.x * CHUNK;

  // stage one sample per thread
  float m = 0.0f;
  {
    int g = base + threadIdx.x;
    float s = 0.0f;
    if (g < N) {
      s = scores[g];
      if (mode == 0)      m = (float)tgt[g];
      else if (mode == 1) m = (float)((const int*)tgt)[g];
      else                m = ((const float*)tgt)[g];
    }
    s_d[threadIdx.x] = make_float2(s, m);
  }
  __syncthreads();
  float cnt = block_sum(m, s_red);  // valid on thread 0 only

  const int k_idx = threadIdx.x & (NK - 1);
  const int half = threadIdx.x >> 7;  // 0 or 1
  const float kf = (float)(k_idx + 1);
  const int HC = CHUNK / 2;           // 128 samples per half
  const int i0 = half * HC;

  float ps0 = 0.f, pc0 = 0.f, ts0 = 0.f, tc0 = 0.f;
  float ps1 = 0.f, pc1 = 0.f, ts1 = 0.f, tc1 = 0.f;
  for (int i = 0; i < HC; i += 8) {
    float2 r[8];
    #pragma unroll
    for (int j = 0; j < 8; ++j) r[j] = s_d[i0 + i + j];  // 4x ds_read_b128 broadcast
    #pragma unroll
    for (int j = 0; j < 8; ++j) {
      float x = kf * r[j].x;
      float f = __builtin_amdgcn_fractf(x);      // k*s mod 1 (revolutions)
      float sn = __builtin_amdgcn_sinf(f);       // sin(2*pi*k*s)
      float cs = __builtin_amdgcn_cosf(f);       // cos(2*pi*k*s)
      if (j & 1) {
        ts1 += sn; tc1 += cs;
        ps1 = fmaf(r[j].y, sn, ps1); pc1 = fmaf(r[j].y, cs, pc1);
      } else {
        ts0 += sn; tc0 += cs;
        ps0 = fmaf(r[j].y, sn, ps0); pc0 = fmaf(r[j].y, cs, pc0);
      }
    }
  }
  float ps = ps0 + ps1, pc = pc0 + pc1, ts = ts0 + ts1, tc = tc0 + tc1;
  // padded (g>=N) entries have s=0,m=0 -> contributed cos(0)=1 to tc only; remove
  int valid = min(max(N - base - i0, 0), HC);
  tc -= (float)(HC - valid);

  if (half == 1) {
    s_comb[k_idx * 4 + 0] = ps;
    s_comb[k_idx * 4 + 1] = pc;
    s_comb[k_idx * 4 + 2] = ts;
    s_comb[k_idx * 4 + 3] = tc;
  }
  __syncthreads();
  float* ab = acc + (size_t)(blockIdx.x & (REP - 1)) * RSTRIDE;
  if (half == 0) {
    atomicAdd(&ab[k_idx * 4 + 0], ps + s_comb[k_idx * 4 + 0]);
    atomicAdd(&ab[k_idx * 4 + 1], pc + s_comb[k_idx * 4 + 1]);
    atomicAdd(&ab[k_idx * 4 + 2], ts + s_comb[k_idx * 4 + 2]);
    atomicAdd(&ab[k_idx * 4 + 3], tc + s_comb[k_idx * 4 + 3]);
  }
  if (threadIdx.x == 0) atomicAdd(&ab[NK * 4], cnt);
}

// ---- phase 2: sum replicas, coefficients, CDF eval, AUC ----
__global__ __launch_bounds__(K2_TPB) void k_final(const float* __restrict__ acc,
                                                  int N,
                                                  float* __restrict__ out) {
  __shared__ float s_sums[NK * 4];
  __shared__ float s_isp[NK], s_icp[NK], s_isn[NK], s_icn[NK];
  __shared__ float s_pn[NSTEPS + 2], s_nn[NSTEPS + 2];
  __shared__ float s_red[K2_TPB / 64];
  __shared__ float s_npos;
  const int tid = threadIdx.x;

  if (tid < NK * 4) {
    float v = 0.0f;
    #pragma unroll
    for (int r = 0; r < REP; ++r) v += acc[r * RSTRIDE + tid];
    s_sums[tid] = v;
  }
  if (tid == 0) {
    float v = 0.0f;
    #pragma unroll
    for (int r = 0; r < REP; ++r) v += acc[r * RSTRIDE + NK * 4];
    s_npos = v;
  }
  __syncthreads();

  // integrated Fourier coefficients for both classes
  if (tid < NK) {
    const float eps = 1.1920929e-07f;  // FLT_EPSILON, matches jnp.finfo(f32).eps
    float npos = s_npos;
    float nneg = (float)N - npos;
    float sp = s_sums[tid * 4 + 0], cp = s_sums[tid * 4 + 1];
    float st = s_sums[tid * 4 + 2], ct = s_sums[tid * 4 + 3];
    float scp, ccp, scn, ccn;
    if (npos < eps) { scp = 0.0f; ccp = 0.0f; }
    else { float d = fmaxf(npos, eps); scp = sp / d; ccp = cp / d; }
    if (nneg < eps) { scn = 0.0f; ccn = 0.0f; }
    else { float d = fmaxf(nneg, eps); scn = (st - sp) / d; ccn = (ct - cp) / d; }
    float w = 6.2831853071795864769f * (float)(tid + 1);  // fl(2*pi)*k, as reference
    s_isp[tid] = ccp / w;  s_icp[tid] = -scp / w;
    s_isn[tid] = ccn / w;  s_icn[tid] = -scn / w;
  }
  __syncthreads();

  // normalized CDFs at 1024 thresholds, one per thread
  {
    float thr = (float)tid * (1.0f / 1023.0f);
    float cp_acc = 0.0f, cn_acc = 0.0f;
    #pragma unroll 4
    for (int k = 0; k < NK; ++k) {
      float x = (float)(k + 1) * thr;
      float f = __builtin_amdgcn_fractf(x);
      float sn = __builtin_amdgcn_sinf(f);
      float cs = __builtin_amdgcn_cosf(f);
      cp_acc += sn * s_isp[k] + cs * s_icp[k];
      cn_acc += sn * s_isn[k] + cs * s_icn[k];
    }
    s_pn[tid + 1] = 1.0f - 0.5f * (cp_acc + 0.5f);
    s_nn[tid + 1] = 1.0f - 0.5f * (cn_acc + 0.5f);
  }
  if (tid == 0) {
    s_pn[0] = 1.0f; s_nn[0] = 1.0f;
    s_pn[NSTEPS + 1] = 0.0f; s_nn[NSTEPS + 1] = 0.0f;
  }
  __syncthreads();

  // Riemann AUC both directions
  float pa = 0.0f, na = 0.0f;
  for (int i = tid; i < NSTEPS + 1; i += K2_TPB) {
    float p0 = s_pn[i], p1 = s_pn[i + 1];
    float n0 = s_nn[i], n1 = s_nn[i + 1];
    pa = fmaf(p0, n0 - n1, pa);   // pos_norm[i] * (-diff(neg_norm))[i]
    na = fmaf(n0, p1 - p0, na);   // neg_norm[i] * diff(pos_norm)[i]
  }
  float paS = block_sum(pa, s_red);
  __syncthreads();
  float naS = block_sum(na, s_red);
  if (tid == 0) out[0] = 0.5f * (paS + (1.0f + naS));
}

extern "C" void kernel_launch(void* const* d_in, const int* in_sizes, int n_in,
                              void* d_out, int out_size, void* d_ws, size_t ws_size,
                              hipStream_t stream) {
  const float* scores = (const float*)d_in[0];
  const unsigned char* targets = (const unsigned char*)d_in[1];
  const int N = in_sizes[0];

  unsigned* flags = (unsigned*)d_ws;                 // 64 words
  float* acc = (float*)((char*)d_ws + 512);          // REP*RSTRIDE floats

  const int nblocks = (N + CHUNK - 1) / CHUNK;       // 1024 for N=262144

  k_detect<<<DET_BLOCKS, DET_TPB, 0, stream>>>(targets, N, flags, acc);
  k_partial<<<nblocks, K1_TPB, 0, stream>>>(scores, targets, N, flags, acc);
  k_final<<<1, K2_TPB, 0, stream>>>(acc, N, (float*)d_out);
}